// Round 4
// baseline (38667.212 us; speedup 1.0000x reference)
//
#include <hip/hip_runtime.h>
#include <cfloat>
#include <math.h>

#define N 512
#define NW 8   // columns per lane (64 lanes x 8 = 512)

__device__ __forceinline__ unsigned long long map_f64(double x) {
    unsigned long long b = (unsigned long long)__double_as_longlong(x);
    return b ^ ((b >> 63) ? 0xFFFFFFFFFFFFFFFFull : 0x8000000000000000ull);
}
__device__ __forceinline__ double unmap_f64(unsigned long long b) {
    b ^= ((b >> 63) ? 0x8000000000000000ull : 0xFFFFFFFFFFFFFFFFull);
    return __longlong_as_double((long long)b);
}

// Single-wave exact JV solver, all data LDS-resident (no global in hot loop).
// Lane owns cols lane*8+1..lane*8+8. Warm start: column reduction (squared-
// distance argmin, sqrt once at the end — monotone, so identical v) + greedy
// tight matching + LAPJV augmenting row reduction. Then exact Dijkstra with
// same-address ds_min_u64 reduce; key = [45b value | 9b col-1 | 10b p[col]].
__global__ __launch_bounds__(64, 1) void tofu_solver(
    const float* __restrict__ dgm, const float* __restrict__ dgm_x,
    float* __restrict__ out)
{
#pragma clang fp contract(off)
    __shared__ double2 pt[N];          // row points (b,d), f64
    __shared__ double  u_lds[N + 1];
    __shared__ int     p_lds[N + 1];
    __shared__ int     way_lds[N + 1];
    __shared__ int     claim[N + 1];
    __shared__ int     flist[4 * N + 32];
    __shared__ unsigned long long slot[2];
    __shared__ int     nfree_s;

    const int lane = threadIdx.x;      // 0..63
    const float2* dgm2  = (const float2*)dgm;
    const float2* dgmx2 = (const float2*)dgm_x;

    double xb[NW], xd[NW], v[NW], minv[NW], du[NW];
    int pcol[NW], amin[NW];

    // ---- stage: rows -> LDS (coalesced), own columns' points -> registers ----
    #pragma unroll
    for (int s = 0; s < NW; ++s) {
        const int r = s * 64 + lane;
        const float2 p2 = dgm2[r];
        pt[r] = make_double2((double)p2.x, (double)p2.y);
        const float2 q2 = dgmx2[lane * NW + s];
        xb[s] = (double)q2.x; xd[s] = (double)q2.y;
    }
    for (int k = lane; k <= N; k += 64) {
        u_lds[k] = 0.0; p_lds[k] = 0; way_lds[k] = 0; claim[k] = 0x7fffffff;
    }
    if (lane == 0) { slot[0] = ~0ull; slot[1] = ~0ull; }
    __syncthreads();

    // ---- column reduction: argmin over squared distance (monotone == sqrt) ----
    {
        double vsq[NW];
        #pragma unroll
        for (int s = 0; s < NW; ++s) { vsq[s] = DBL_MAX; amin[s] = 1; }
        for (int i = 0; i < N; ++i) {
            const double2 rp = pt[i];              // broadcast b128
            #pragma unroll
            for (int s = 0; s < NW; ++s) {
                const double db = rp.x - xb[s];
                const double dd = rp.y - xd[s];
                const double sq = db * db + dd * dd;
                if (sq < vsq[s]) { vsq[s] = sq; amin[s] = i + 1; }
            }
        }
        #pragma unroll
        for (int s = 0; s < NW; ++s) v[s] = sqrt(vsq[s]);  // exact IEEE sqrt of min
    }

    // ---- greedy tight matching: row r -> smallest col whose argmin is r ----
    #pragma unroll
    for (int s = 0; s < NW; ++s)
        atomicMin(&claim[amin[s]], lane * NW + s + 1);
    __syncthreads();
    #pragma unroll
    for (int s = 0; s < NW; ++s) {
        const int col = lane * NW + s + 1;
        if (claim[amin[s]] == col) p_lds[col] = amin[s];   // edge tight: c=v[j], u=0
    }
    __syncthreads();
    // freelist of unmatched rows
    for (int s = 0; s < NW; ++s) claim[lane * NW + s + 1] = 0;
    __syncthreads();
    for (int s = 0; s < NW; ++s) {
        const int r = p_lds[lane * NW + s + 1];
        if (r) claim[r] = 1;
    }
    __syncthreads();
    if (lane == 0) {
        int nf = 0;
        for (int r = 1; r <= N; ++r) if (!claim[r]) flist[nf++] = r;
        nfree_s = nf;
    }
    __syncthreads();

    // ---- LAPJV augmenting row reduction (feasibility-preserving, capped) ----
    {
        int head = 0, tail = nfree_s;
        const int cap = 3 * tail + 16;
        for (int step = 0; step < cap && head < tail; ++step) {
            const int i = flist[head++];                   // uniform broadcast
            const double2 rp = pt[i - 1];
            double v1 = DBL_MAX, m2 = DBL_MAX; int j1 = N + 1;
            #pragma unroll
            for (int s = 0; s < NW; ++s) {
                const double db = rp.x - xb[s];
                const double dd = rp.y - xd[s];
                const double val = sqrt(db * db + dd * dd) - v[s];
                const int col = lane * NW + s + 1;
                if (val < v1 || (val == v1 && col < j1)) { m2 = v1; v1 = val; j1 = col; }
                else if (val < m2) m2 = val;
            }
            #pragma unroll
            for (int m = 32; m >= 1; m >>= 1) {            // exact f64 pair reduce
                const double ov1 = __shfl_xor(v1, m, 64);
                const double om2 = __shfl_xor(m2, m, 64);
                const int    oj1 = __shfl_xor(j1, m, 64);
                if (ov1 < v1 || (ov1 == v1 && oj1 < j1)) {
                    m2 = fmin(v1, fmin(om2, m2));
                    v1 = ov1; j1 = oj1;
                } else {
                    m2 = fmin(m2, fmin(ov1, om2));
                }
            }
            const int k_old = p_lds[j1];                   // uniform, pre-write
            if (((j1 - 1) >> 3) == lane && m2 > v1) v[(j1 - 1) & 7] -= (m2 - v1);
            if (lane == 0) {
                u_lds[i] = m2;                             // feasible; tight on j1
                p_lds[j1] = i;
                if (k_old) flist[tail] = k_old;
            }
            if (k_old) ++tail;                             // uniform
            __syncthreads();
        }
    }

    // ---- rebuild freelist from p ----
    for (int s = 0; s < NW; ++s) claim[lane * NW + s + 1] = 0;
    __syncthreads();
    for (int s = 0; s < NW; ++s) {
        const int r = p_lds[lane * NW + s + 1];
        if (r) claim[r] = 1;
    }
    __syncthreads();
    if (lane == 0) {
        int nf = 0;
        for (int r = 1; r <= N; ++r) if (!claim[r]) flist[nf++] = r;
        nfree_s = nf;
    }
    __syncthreads();
    const int nfree = nfree_s;

    // ---- exact Dijkstra phase (LDS recompute, ds_min_u64 reduce) ----
    for (int kk = 0; kk < nfree; ++kk) {
        const int iroot = flist[kk];
        #pragma unroll
        for (int s = 0; s < NW; ++s) {
            pcol[s] = p_lds[lane * NW + s + 1];    // static during this Dijkstra
            minv[s] = DBL_MAX;
            du[s] = 0.0;
        }
        double du0 = 0.0;
        if (lane == 0) p_lds[0] = iroot;           // augment-chain terminator
        __syncthreads();

        int i0 = iroot, juse = 0, par = 0, used = 0;
        while (true) {
            if (juse) {                            // mark prev winner used
                const int sl = juse - 1 - lane * NW;
                if ((unsigned)sl < NW) used |= (1 << sl);
            }
            const double2 rp = pt[i0 - 1];         // broadcast b128
            const double u_i0 = u_lds[i0];         // broadcast b64
            unsigned long long kbest = ~0ull;
            #pragma unroll
            for (int s = 0; s < NW; ++s) {
                if (!((used >> s) & 1)) {
                    const double db = rp.x - xb[s];
                    const double dd = rp.y - xd[s];
                    const double c  = sqrt(db * db + dd * dd);
                    const double cur = (c - u_i0) - v[s];
                    if (cur < minv[s]) { minv[s] = cur; way_lds[lane * NW + s + 1] = juse; }
                    const unsigned long long k =
                        (map_f64(minv[s]) & ~0x7FFFFull)
                        | ((unsigned long long)(lane * NW + s) << 10)
                        | (unsigned long long)pcol[s];
                    if (k < kbest) kbest = k;
                }
            }
            atomicMin(&slot[par], kbest);          // same-address ds_min_u64
            __syncthreads();                       // single-wave: ~free
            const unsigned long long key = slot[par];
            if (lane == 0) slot[par] = ~0ull;      // reset for 2 iters later
            par ^= 1;
            const double delta = unmap_f64(key & ~0x7FFFFull);  // <= all true minv
            #pragma unroll
            for (int s = 0; s < NW; ++s) {
                if ((used >> s) & 1) { v[s] -= delta; du[s] += delta; }
                else                 { minv[s] -= delta; }
            }
            if (lane == 0) du0 += delta;
            juse = (int)((key >> 10) & 511) + 1;
            i0   = (int)(key & 1023);              // p[j1] payload; 0 => augment
            if (i0 == 0) break;
        }
        // flush register-accumulated duals (distinct rows -> race-free)
        #pragma unroll
        for (int s = 0; s < NW; ++s)
            if ((used >> s) & 1) u_lds[pcol[s]] += du[s];
        if (lane == 0) {
            u_lds[iroot] += du0;
            int j = juse;                          // augment along way[]
            while (j) { const int jn = way_lds[j]; p_lds[j] = p_lds[jn]; j = jn; }
        }
        __syncthreads();
    }

    // ---- loss = 0.5 * sum_j ||dgm[p[j]-1] - dgm_x[j-1]||^2 (f32 diffs) ----
    double acc = 0.0;
    for (int s = 0; s < NW; ++s) {
        const int j = lane * NW + s;
        const int r = p_lds[j + 1] - 1;
        const float2 a = dgm2[r];
        const float2 b = dgmx2[j];
        const float fb = a.x - b.x;
        const float fd = a.y - b.y;
        acc += (double)fb * (double)fb + (double)fd * (double)fd;
    }
    #pragma unroll
    for (int m = 32; m >= 1; m >>= 1) acc += __shfl_xor(acc, m, 64);
    if (lane == 0) out[0] = (float)(0.5 * acc);
}

extern "C" void kernel_launch(void* const* d_in, const int* in_sizes, int n_in,
                              void* d_out, int out_size, void* d_ws, size_t ws_size,
                              hipStream_t stream) {
    const float* dgm   = (const float*)d_in[0];
    const float* dgm_x = (const float*)d_in[1];
    float* out = (float*)d_out;
    tofu_solver<<<1, 64, 0, stream>>>(dgm, dgm_x, out);
}

// Round 5
// 5752.488 us; speedup vs baseline: 6.7218x; 6.7218x over previous
//
#include <hip/hip_runtime.h>
#include <cfloat>
#include <math.h>

#define N 512
typedef unsigned long long u64_t;

__device__ __forceinline__ u64_t map_f64(double x) {
    u64_t b = (u64_t)__double_as_longlong(x);
    return b ^ ((b >> 63) ? 0xFFFFFFFFFFFFFFFFull : 0x8000000000000000ull);
}
__device__ __forceinline__ double unmap_f64(u64_t b) {
    b ^= ((b >> 63) ? 0x8000000000000000ull : 0xFFFFFFFFFFFFFFFFull);
    return __longlong_as_double((long long)b);
}

// wave64 u64 min-reduce via DPP (VALU pipe, ~90cy). Valid result in lane 63.
// row_shr:1/2/4/8 reduce within 16-lane rows; row_bcast:15/31 merge rows.
// bound_ctrl=false + old=own value => lanes w/o source keep own (min identity).
__device__ __forceinline__ u64_t wave_min_key(u64_t key) {
    unsigned hi = (unsigned)(key >> 32), lo = (unsigned)key;
#define MIN_STAGE(CTRL)                                                        \
    {                                                                          \
        unsigned oh = (unsigned)__builtin_amdgcn_update_dpp((int)hi, (int)hi,  \
                                                            CTRL, 0xF, 0xF, false); \
        unsigned ol = (unsigned)__builtin_amdgcn_update_dpp((int)lo, (int)lo,  \
                                                            CTRL, 0xF, 0xF, false); \
        const u64_t o = ((u64_t)oh << 32) | ol;                                \
        const u64_t c = ((u64_t)hi << 32) | lo;                                \
        if (o < c) { hi = oh; lo = ol; }                                       \
    }
    MIN_STAGE(0x111) MIN_STAGE(0x112) MIN_STAGE(0x114) MIN_STAGE(0x118)
    MIN_STAGE(0x142) MIN_STAGE(0x143)
#undef MIN_STAGE
    return ((u64_t)hi << 32) | lo;
}

// 512 threads / 8 waves, thread t owns column t+1. Exact JV:
// column reduction + greedy tight match + LAPJV ARR warm start, then
// Dijkstra with DPP wave-reduce + 8-way ds_min_u64 combine.
// key = [45b value | 9b col-1 | 10b p[col]] (truncation precedent: R3/R4 absmax 0).
__global__ __launch_bounds__(512, 1) void tofu_solver(
    const float* __restrict__ dgm, const float* __restrict__ dgm_x,
    float* __restrict__ out)
{
#pragma clang fp contract(off)
    __shared__ double2 pt[N];
    __shared__ double  u_lds[N + 1];
    __shared__ int     p_lds[N + 1];
    __shared__ int     way_lds[N + 1];
    __shared__ int     claim[N + 1];
    __shared__ int     flist[4 * N + 32];
    __shared__ u64_t   dslot[3];        // Dijkstra combine slots (mod-3 rotation)
    __shared__ u64_t   aslot[2], bslot[2];  // ARR slots (parity)
    __shared__ double  v1x;
    __shared__ double  red8[8];
    __shared__ int     nfree_s;

    const int tid  = threadIdx.x;       // 0..511
    const int col  = tid + 1;           // 1..512
    const int lane = tid & 63;
    const int wid  = tid >> 6;
    const float2* dgm2  = (const float2*)dgm;
    const float2* dgmx2 = (const float2*)dgm_x;

    // ---- stage points; own column's target point in registers ----
    {
        const float2 p2 = dgm2[tid];
        pt[tid] = make_double2((double)p2.x, (double)p2.y);
    }
    const float2 q2 = dgmx2[tid];
    const double xb = (double)q2.x, xd = (double)q2.y;
    u_lds[col] = 0.0; p_lds[col] = 0; way_lds[col] = 0; claim[col] = 0x7fffffff;
    if (tid == 0) {
        u_lds[0] = 0.0; p_lds[0] = 0; way_lds[0] = 0; claim[0] = 0x7fffffff;
        dslot[0] = dslot[1] = dslot[2] = ~0ull;
        aslot[0] = aslot[1] = ~0ull; bslot[0] = bslot[1] = ~0ull;
    }
    __syncthreads();

    // ---- column reduction: argmin over squared dist (sqrt monotone => same v) ----
    double v_j; int amin;
    {
        double vsq = DBL_MAX; amin = 1;
        for (int i = 0; i < N; ++i) {
            const double2 rp = pt[i];                 // broadcast b128
            const double db = rp.x - xb, dd = rp.y - xd;
            const double sq = db * db + dd * dd;
            if (sq < vsq) { vsq = sq; amin = i + 1; }
        }
        v_j = sqrt(vsq);                              // exact: sqrt(min) == min(sqrt)
    }

    // ---- greedy tight matching: row r -> smallest col whose argmin is r ----
    atomicMin(&claim[amin], col);
    __syncthreads();
    if (claim[amin] == col) p_lds[col] = amin;        // tight: c=v[col], u=0
    __syncthreads();
    // freelist of unmatched rows
    claim[col] = 0;
    __syncthreads();
    { const int r = p_lds[col]; if (r) claim[r] = 1; }
    __syncthreads();
    if (tid == 0) {
        int nf = 0;
        for (int r = 1; r <= N; ++r) if (!claim[r]) flist[nf++] = r;
        nfree_s = nf;
    }
    __syncthreads();

    // ---- LAPJV augmenting row reduction (exactness-preserving, capped) ----
    {
        int head = 0, tail = nfree_s, q = 0;
        const int cap = 3 * tail + 16;
        int myp = p_lds[col];                          // register copy of p[col]
        for (int step = 0; step < cap && head < tail; ++step) {
            const int i = flist[head++];               // uniform broadcast
            const double2 rp = pt[i - 1];
            const double db = rp.x - xb, dd = rp.y - xd;
            const double val = sqrt(db * db + dd * dd) - v_j;   // exact f64
            const u64_t key = (map_f64(val) & ~0x7FFFFull)
                            | ((u64_t)(col - 1) << 10) | (u64_t)myp;
            u64_t kr = wave_min_key(key);
            if (lane == 63) atomicMin(&aslot[q], kr);
            __syncthreads();                           // barrier 1
            const u64_t k1 = aslot[q];
            const int j1    = (int)((k1 >> 10) & 511) + 1;
            const int k_old = (int)(k1 & 1023);
            if (col == j1) v1x = val;                  // exact v1 handoff
            kr = wave_min_key((col == j1) ? ~0ull : key);
            if (lane == 63) atomicMin(&bslot[q], kr);
            __syncthreads();                           // barrier 2
            const double m2t = unmap_f64(bslot[q] & ~0x7FFFFull);  // <= true 2nd-min
            const double v1e = v1x;
            const double ui  = fmax(m2t, v1e);         // feasible AND tight on j1
            if (col == j1) { v_j -= (ui - val); myp = i; }
            if (tid == 0) {
                u_lds[i] = ui;
                p_lds[j1] = i;
                if (k_old) flist[tail] = k_old;
                aslot[q ^ 1] = ~0ull; bslot[q ^ 1] = ~0ull;  // safe: 2 barriers since last read
            }
            if (k_old) ++tail;                         // uniform
            q ^= 1;
            __syncthreads();                           // barrier 3
        }
    }

    // ---- rebuild freelist from p ----
    claim[col] = 0;
    __syncthreads();
    { const int r = p_lds[col]; if (r) claim[r] = 1; }
    __syncthreads();
    if (tid == 0) {
        int nf = 0;
        for (int r = 1; r <= N; ++r) if (!claim[r]) flist[nf++] = r;
        nfree_s = nf;
    }
    __syncthreads();
    const int nfree = nfree_s;

    // ---- exact Dijkstra phase ----
    for (int kk = 0; kk < nfree; ++kk) {
        const int iroot = flist[kk];                   // ordered by prev end barrier
        const int pcol  = p_lds[col];                  // static during this Dijkstra
        if (tid == 0) p_lds[0] = iroot;                // only tid0 reads p[0] (augment)
        double minv = DBL_MAX, du = 0.0, du0 = 0.0;
        bool used = false;
        int juse = 0, i0 = iroot, par = 0;

        while (true) {
            // ---- A-phase ----
            if (col == juse) used = true;              // mark prev winner
            const double2 rp = pt[i0 - 1];             // broadcast b128
            const double u0 = u_lds[i0];               // untouched this Dijkstra
            u64_t key = ~0ull;
            if (!used) {
                const double db = rp.x - xb, dd = rp.y - xd;
                const double c = sqrt(db * db + dd * dd);
                const double cur = (c - u0) - v_j;
                if (cur < minv) { minv = cur; way_lds[col] = juse; }
                key = (map_f64(minv) & ~0x7FFFFull)
                    | ((u64_t)(col - 1) << 10) | (u64_t)pcol;
            }
            key = wave_min_key(key);
            if (lane == 63) atomicMin(&dslot[par], key);
            __syncthreads();
            // ---- B-phase ----
            const u64_t k = dslot[par];
            if (tid == 0) dslot[(par + 2) % 3] = ~0ull;  // last read 2 barriers ago
            const double delta = unmap_f64(k & ~0x7FFFFull);  // <= every free minv
            if (used) { v_j -= delta; du += delta; }
            else        minv -= delta;
            if (tid == 0) du0 += delta;
            juse = (int)((k >> 10) & 511) + 1;
            i0   = (int)(k & 1023);                    // p payload; 0 => free col
            if (i0 == 0) break;
            par = (par + 1) % 3;
        }

        // epilogue: flush duals (distinct rows => race-free), augment, clean slot
        if (used) u_lds[pcol] += du;
        if (tid == 0) {
            u_lds[iroot] += du0;
            dslot[par] = ~0ull;                        // the slot just consumed
            int j = juse;
            while (j) { const int jn = way_lds[j]; p_lds[j] = p_lds[jn]; j = jn; }
        }
        __syncthreads();
    }

    // ---- loss = 0.5 * sum_j ||dgm[p[j]-1] - dgm_x[j-1]||^2 (f32 diffs like ref) ----
    const int r = p_lds[col] - 1;
    const float2 a = dgm2[r];
    const float2 b = dgmx2[tid];
    const float fb = a.x - b.x;
    const float fd = a.y - b.y;
    double acc = (double)fb * (double)fb + (double)fd * (double)fd;
    #pragma unroll
    for (int m = 32; m >= 1; m >>= 1) acc += __shfl_xor(acc, m, 64);
    if (lane == 0) red8[wid] = acc;
    __syncthreads();
    if (tid == 0) {
        double s = 0.0;
        #pragma unroll
        for (int w = 0; w < 8; ++w) s += red8[w];
        out[0] = (float)(0.5 * s);
    }
}

extern "C" void kernel_launch(void* const* d_in, const int* in_sizes, int n_in,
                              void* d_out, int out_size, void* d_ws, size_t ws_size,
                              hipStream_t stream) {
    const float* dgm   = (const float*)d_in[0];
    const float* dgm_x = (const float*)d_in[1];
    float* out = (float*)d_out;
    tofu_solver<<<1, 512, 0, stream>>>(dgm, dgm_x, out);
}